// Round 1
// baseline (1537.911 us; speedup 1.0000x reference)
//
#include <hip/hip_runtime.h>
#include <cfloat>
#include <math.h>

#define K_EMB 512
#define CDIM  64
#define HW    4096        // 64*64 spatial per batch
#define NPOS  131072      // 32*64*64 rows
#define NELEM 8388608     // NPOS*CDIM

// ws layout: [0,2048) float cnorm[512] ; [2048,4096) int counts[512] ; [4096,4100) float loss_acc

__global__ __launch_bounds__(512) void vq_prep(const float* __restrict__ cb,
                                               float* __restrict__ cnorm,
                                               int* __restrict__ counts,
                                               float* __restrict__ loss_acc) {
    int k = threadIdx.x;
    if (k < K_EMB) {
        float s = 0.f;
        #pragma unroll
        for (int c = 0; c < CDIM; ++c) { float v = cb[k * CDIM + c]; s = fmaf(v, v, s); }
        cnorm[k] = 0.5f * s;
        counts[k] = 0;
    }
    if (k == 0) *loss_acc = 0.f;
}

__global__ __launch_bounds__(256) void vq_main(const float* __restrict__ z,
                                               const float* __restrict__ cb,
                                               const float* __restrict__ cnorm,
                                               float* __restrict__ out,
                                               int* __restrict__ counts,
                                               float* __restrict__ loss_acc) {
    __shared__ int   hist[K_EMB];
    __shared__ float red[256];
    for (int i = threadIdx.x; i < K_EMB; i += 256) hist[i] = 0;
    __syncthreads();

    int p  = blockIdx.x * 256 + threadIdx.x;   // row = b*4096 + hw (blocks never straddle b: 256|4096)
    int b  = p >> 12;
    int hw = p & 4095;
    const float* zp = z + (size_t)b * (CDIM * HW) + hw;

    float zr[CDIM];
    #pragma unroll
    for (int c = 0; c < CDIM; ++c) zr[c] = zp[(size_t)c * HW];   // coalesced per c

    // fp32 pass: argmin_k ( 0.5*||c_k||^2 - z.c_k ), track top-2 for safety margin
    float best = FLT_MAX, second = FLT_MAX;
    int bidx = 0;
    for (int k = 0; k < K_EMB; ++k) {
        const float* ck = cb + k * CDIM;       // wave-uniform address -> s_load expected
        float a0 = 0.f, a1 = 0.f, a2 = 0.f, a3 = 0.f;
        #pragma unroll
        for (int c = 0; c < CDIM; c += 4) {
            a0 = fmaf(zr[c + 0], ck[c + 0], a0);
            a1 = fmaf(zr[c + 1], ck[c + 1], a1);
            a2 = fmaf(zr[c + 2], ck[c + 2], a2);
            a3 = fmaf(zr[c + 3], ck[c + 3], a3);
        }
        float acc = cnorm[k] - ((a0 + a1) + (a2 + a3));
        bool lt = acc < best;
        second = lt ? best : fminf(second, acc);
        bidx   = lt ? k    : bidx;
        best   = lt ? acc  : best;
    }

    // near-tie: resolve in fp64 (exact vs high-precision reference; rare path)
    if (second - best < 1e-5f) {
        double bestd = DBL_MAX; int bi = 0;
        for (int k = 0; k < K_EMB; ++k) {
            const float* ck = cb + k * CDIM;
            double dd = 0.0;
            #pragma unroll 8
            for (int c = 0; c < CDIM; ++c) {
                double cv = (double)ck[c];
                dd += cv * (cv - 2.0 * (double)zr[c]);   // ||c||^2 - 2 z.c
            }
            if (dd < bestd) { bestd = dd; bi = k; }
        }
        bidx = bi;
    }

    // epilogue: quantized_st = z + (q - z)  (match reference rounding), loss partial, histogram
    const float* q  = cb + bidx * CDIM;        // divergent gather, L1/L2-resident (128 KB)
    float*       op = out + (size_t)b * (CDIM * HW) + hw;
    float lsum = 0.f;
    #pragma unroll
    for (int c = 0; c < CDIM; ++c) {
        float qc = q[c];
        float d  = qc - zr[c];
        op[(size_t)c * HW] = zr[c] + d;        // coalesced per c
        lsum = fmaf(d, d, lsum);
    }
    atomicAdd(&hist[bidx], 1);

    red[threadIdx.x] = lsum;
    __syncthreads();                            // also orders hist atomics before flush
    for (int s = 128; s > 0; s >>= 1) {
        if (threadIdx.x < (unsigned)s) red[threadIdx.x] += red[threadIdx.x + s];
        __syncthreads();
    }
    if (threadIdx.x == 0) atomicAdd(loss_acc, red[0]);
    for (int i = threadIdx.x; i < K_EMB; i += 256) {
        int h = hist[i];
        if (h) atomicAdd(&counts[i], h);
    }
}

__global__ __launch_bounds__(512) void vq_final(const int* __restrict__ counts,
                                                const float* __restrict__ loss_acc,
                                                float* __restrict__ out_scalars) {
    __shared__ float red[512];
    int k = threadIdx.x;
    float pr = (float)counts[k] / (float)NPOS;
    red[k] = pr * logf(pr + 1e-10f);
    __syncthreads();
    for (int s = 256; s > 0; s >>= 1) {
        if (k < s) red[k] += red[k + s];
        __syncthreads();
    }
    if (k == 0) {
        float m = *loss_acc / (float)NELEM;
        out_scalars[0] = m + 0.25f * m;       // vq_loss + 0.25*commitment (identical means)
        out_scalars[1] = expf(-red[0]);       // perplexity
    }
}

extern "C" void kernel_launch(void* const* d_in, const int* in_sizes, int n_in,
                              void* d_out, int out_size, void* d_ws, size_t ws_size,
                              hipStream_t stream) {
    const float* z  = (const float*)d_in[0];
    const float* cb = (const float*)d_in[1];
    float* out = (float*)d_out;

    float* cnorm    = (float*)d_ws;
    int*   counts   = (int*)((char*)d_ws + 2048);
    float* loss_acc = (float*)((char*)d_ws + 4096);

    vq_prep<<<1, 512, 0, stream>>>(cb, cnorm, counts, loss_acc);
    vq_main<<<NPOS / 256, 256, 0, stream>>>(z, cb, cnorm, out, counts, loss_acc);
    vq_final<<<1, 512, 0, stream>>>(counts, loss_acc, out + NELEM);
}